// Round 8
// baseline (48.241 us; speedup 1.0000x reference)
//
#include <hip/hip_runtime.h>

typedef float f32x4 __attribute__((ext_vector_type(4)));

static constexpr int B  = 32;
static constexpr int Q  = 900;   // queries (and pseudo targets Qb)
static constexpr int NC = 91;    // classes
static constexpr int T  = 30;    // gt targets
static constexpr int QT = 12;    // q-rows per block in cost kernel (900 = 75*12)

static constexpr float ALPHA_ = 0.25f;
static constexpr float EPS_   = 1e-8f;
static constexpr float BIG_   = 1e9f;

// ---------------------------------------------------------------------------
// K1: one 64-lane wave per (b, qb) of the base model. Coalesced logit read +
// butterfly argmax; one gt target per lane for the keep-mask.
// Mask is correctness-critical: exact IEEE fp32, no contraction, reference
// op order. (Byte-identical to the passing round-7 version.)
// ---------------------------------------------------------------------------
__global__ __launch_bounds__(256) void k1_mask_label(
    const float* __restrict__ logits_base,
    const float4* __restrict__ boxes_base,
    const float4* __restrict__ targets,
    int* __restrict__ labels,
    float* __restrict__ mask_out) {
#pragma clang fp contract(off)
  int wid  = (blockIdx.x * 256 + threadIdx.x) >> 6;
  int lane = threadIdx.x & 63;
  int b = wid / Q;

  const float* row = logits_base + (size_t)wid * NC;
  float v  = (lane < NC) ? row[lane] : -1e30f;
  int  arg = lane;
  int lane2 = lane + 64;
  if (lane2 < NC) {
    float v2 = row[lane2];
    if (v2 > v) { v = v2; arg = lane2; }   // strict >: keep lower idx on tie
  }
  for (int off = 32; off >= 1; off >>= 1) {
    float ov = __shfl_xor(v, off, 64);
    int   oi = __shfl_xor(arg, off, 64);
    if (ov > v || (ov == v && oi < arg)) { v = ov; arg = oi; }
  }
  bool keep = (v > 0.0f);  // sigmoid(max) > 0.5  <=>  max logit > 0

  float4 bb = boxes_base[wid];
  float x1 = bb.x - 0.5f * bb.z, y1 = bb.y - 0.5f * bb.w;
  float x2 = bb.x + 0.5f * bb.z, y2 = bb.y + 0.5f * bb.w;
  float a1 = (x2 - x1) * (y2 - y1);

  bool ok = true;
  if (lane < T) {
    float4 tb = targets[b * T + lane];
    float tx1 = tb.x - 0.5f * tb.z, ty1 = tb.y - 0.5f * tb.w;
    float tx2 = tb.x + 0.5f * tb.z, ty2 = tb.y + 0.5f * tb.w;
    float a2 = (tx2 - tx1) * (ty2 - ty1);
    float ltx = fmaxf(x1, tx1), lty = fmaxf(y1, ty1);
    float rbx = fminf(x2, tx2), rby = fminf(y2, ty2);
    float iw = fmaxf(rbx - ltx, 0.0f), ih = fmaxf(rby - lty, 0.0f);
    float inter = iw * ih;
    float uni = (a1 + a2) - inter;           // reference grouping
    float iou = inter / uni;                 // IEEE divide
    float cx1 = fminf(x1, tx1), cy1 = fminf(y1, ty1);
    float cx2 = fmaxf(x2, tx2), cy2 = fmaxf(y2, ty2);
    float cw = fmaxf(cx2 - cx1, 0.0f), ch = fmaxf(cy2 - cy1, 0.0f);
    float ac = cw * ch;
    float g = iou - (ac - uni) / ac;
    ok = (-g > -0.1f);                       // all(-g > bbox_thresh)
  }
  keep = keep && __all(ok);

  if (lane == 0) {
    labels[wid]   = arg;
    mask_out[wid] = keep ? 1.0f : 0.0f;
  }
}

// focal-style class cost for one logit (tolerance 2e7: fast intrinsics fine)
__device__ __forceinline__ float class_cost(float x) {
  float p   = __builtin_amdgcn_rcpf(1.0f + __expf(-x));
  float omp = 1.0f - p;
  float pos = ALPHA_ * (omp * omp) * (-__logf(p + EPS_));
  float neg = (1.0f - ALPHA_) * (p * p) * (-__logf(omp + EPS_));
  return pos - neg;
}

// ---------------------------------------------------------------------------
// K3: cost matrix. Block = (b, 12 q-rows) x all 900 qb; thread t<225 owns 4
// consecutive qb -> one float4 store per row (PLAIN store: test nt-store
// throttling). Class costs computed from pred_logits in the prologue (cc
// intermediate eliminated: -21 MB HBM + one dispatch). launch_bounds(256,4).
// ---------------------------------------------------------------------------
__global__ __launch_bounds__(256, 4) void k3_cost(
    const float* __restrict__ pred_logits,
    const float4* __restrict__ pred_boxes,
    const float4* __restrict__ boxes_base,
    const int* __restrict__ labels,
    const float* __restrict__ mask_in,
    float* __restrict__ Cout) {
  __shared__ float  s_cc[QT * NC];   // 1092 floats (4.4 KB)
  __shared__ float4 s_e[QT];         // px1, py1, px2, py2
  __shared__ float4 s_m[QT];         // psx=px1+px2, psy, pw, ph
  __shared__ float  s_pa[QT];        // row area

  int b   = blockIdx.x / (Q / QT);
  int q0  = (blockIdx.x % (Q / QT)) * QT;
  int tid = threadIdx.x;

  // stage class costs: nt float4 load of 12x91 logits, transcendental in
  // prologue (~600 cy, hidden by 4 resident blocks/CU)
  const f32x4* lg4 = reinterpret_cast<const f32x4*>(
      pred_logits + ((size_t)(b * Q + q0)) * NC);
  f32x4* sc4 = reinterpret_cast<f32x4*>(s_cc);
  for (int i = tid; i < QT * NC / 4; i += 256) {
    f32x4 v = __builtin_nontemporal_load(lg4 + i);
    f32x4 o;
    o.x = class_cost(v.x);
    o.y = class_cost(v.y);
    o.z = class_cost(v.z);
    o.w = class_cost(v.w);
    sc4[i] = o;
  }

  if (tid < QT) {
    float4 pb = pred_boxes[b * Q + q0 + tid];
    float px1 = pb.x - 0.5f * pb.z, py1 = pb.y - 0.5f * pb.w;
    float px2 = pb.x + 0.5f * pb.z, py2 = pb.y + 0.5f * pb.w;
    s_e[tid]  = make_float4(px1, py1, px2, py2);
    s_m[tid]  = make_float4(px1 + px2, py1 + py2, pb.z, pb.w);
    s_pa[tid] = (px2 - px1) * (py2 - py1);
  }

  // per-thread qb-side state: 4 consecutive columns
  bool active = (tid < Q / 4);  // 225
  float x1b[4], y1b[4], x2b[4], y2b[4], wb[4], hb[4], c2big[4];
  const float* pk[4];
  int jbase = b * Q + 4 * tid;
  if (active) {
    int4 lbv = *reinterpret_cast<const int4*>(labels + jbase);
    float4 mkv = *reinterpret_cast<const float4*>(mask_in + jbase);
    pk[0] = s_cc + lbv.x; pk[1] = s_cc + lbv.y;
    pk[2] = s_cc + lbv.z; pk[3] = s_cc + lbv.w;
    c2big[0] = 2.0f + (mkv.x != 0.0f ? 0.0f : BIG_);
    c2big[1] = 2.0f + (mkv.y != 0.0f ? 0.0f : BIG_);
    c2big[2] = 2.0f + (mkv.z != 0.0f ? 0.0f : BIG_);
    c2big[3] = 2.0f + (mkv.w != 0.0f ? 0.0f : BIG_);
#pragma unroll
    for (int k = 0; k < 4; ++k) {
      float4 bb = boxes_base[jbase + k];
      x1b[k] = bb.x - 0.5f * bb.z; y1b[k] = bb.y - 0.5f * bb.w;
      x2b[k] = bb.x + 0.5f * bb.z; y2b[k] = bb.y + 0.5f * bb.w;
      wb[k]  = bb.z; hb[k] = bb.w;
    }
  }
  __syncthreads();

  if (active) {
    size_t rowbase = ((size_t)(b * Q + q0)) * Q + 4 * tid;
#pragma unroll
    for (int qi = 0; qi < QT; ++qi, rowbase += Q) {
      float4 pe = s_e[qi];
      float4 pm = s_m[qi];
      float  pa = s_pa[qi];
      float res[4];
#pragma unroll
      for (int k = 0; k < 4; ++k) {
        float cls = pk[k][qi * NC];  // ds_read, immediate offset qi*364
        float dx = pm.x - (x1b[k] + x2b[k]);
        float dy = pm.y - (y1b[k] + y2b[k]);
        float dw = pm.z - wb[k];
        float dh = pm.w - hb[k];
        float l1 = fmaf(0.5f, fabsf(dx) + fabsf(dy), fabsf(dw) + fabsf(dh));
        float mwx = fminf(pe.z, x2b[k]) - fmaxf(pe.x, x1b[k]);
        float mwy = fminf(pe.w, y2b[k]) - fmaxf(pe.y, y1b[k]);
        float inter = fmaxf(mwx, 0.0f) * fmaxf(mwy, 0.0f);
        float uni = fmaf(wb[k], hb[k], pa) - inter;
        float cw = (pm.z + wb[k]) - mwx;
        float ch = (pm.w + hb[k]) - mwy;
        float acl = cw * ch;
        float r = __builtin_amdgcn_rcpf(uni * acl);
        float t = fmaf(inter, acl, uni * uni) * r;
        res[k] = fmaf(-2.0f, t, fmaf(5.0f, l1, fmaf(2.0f, cls, c2big[k])));
      }
      // PLAIN store (not nt): writes drain through L2 like fillBuffer's 6.9 TB/s
      *reinterpret_cast<float4*>(Cout + rowbase) =
          make_float4(res[0], res[1], res[2], res[3]);
    }
  }
}

extern "C" void kernel_launch(void* const* d_in, const int* in_sizes, int n_in,
                              void* d_out, int out_size, void* d_ws, size_t ws_size,
                              hipStream_t stream) {
  const float*  pred_logits      = (const float*)d_in[0];
  const float4* pred_boxes       = (const float4*)d_in[1];
  const float*  pred_logits_base = (const float*)d_in[2];
  const float4* pred_boxes_base  = (const float4*)d_in[3];
  const float4* targets          = (const float4*)d_in[4];

  float* out      = (float*)d_out;
  float* mask_out = out + (size_t)B * Q * Q;  // output 1, after C

  int* labels = (int*)d_ws;  // 28800 ints

  k1_mask_label<<<(B * Q) / 4, 256, 0, stream>>>(
      pred_logits_base, pred_boxes_base, targets, labels, mask_out);

  k3_cost<<<B * (Q / QT), 256, 0, stream>>>(
      pred_logits, pred_boxes, pred_boxes_base, labels, mask_out, out);
}